// Round 9
// baseline (60.023 us; speedup 1.0000x reference)
//
#include <hip/hip_runtime.h>
#include <stdint.h>

#define HGT 100
#define WID 152
#define HW (HGT * WID)        // 15200
#define NINST 500
#define NPARAMS 169
#define NQ 126                // fixed quad slots (ceil splits of 500 by image, <=126)
#define QS 12288              // bytes per quad in frag region
#define FRAG_OFS 4096
// per-quad frag layout (bytes):
//   A0   @0     (64 lanes * 16B)   layer0 A-frag, K=16: [f0..f7, Chi, Clo, Exhi, Exlo, Eyhi, Eylo, 0, 0]
//   A1a  @1024  (64*16)            layer1 A-frag k=0..15  (block-diag W1, inst 0,1)
//   A1b  @2048  (64*16)            layer1 A-frag k=16..31 (inst 2,3)
//   bias1@3072  (64*64)            per-lane f32x16 C-operand for layer1 MFMA
//   w2   @7168  (64*64)            per-lane f32x16 layer2 weights
//   meta @11264 (48B)              u32 ofs[4] (n*HW*4 or -1), f32 b2[4], u32 img

typedef __fp16 f16x8  __attribute__((ext_vector_type(8)));
typedef float  f32x16 __attribute__((ext_vector_type(16)));

static __device__ __forceinline__ uint32_t pkh(float lo, float hi) {
    __fp16 a = (__fp16)lo, b = (__fp16)hi;   // RNE
    uint16_t ua = __builtin_bit_cast(uint16_t, a);
    uint16_t ub = __builtin_bit_cast(uint16_t, b);
    return (uint32_t)ua | ((uint32_t)ub << 16);
}

// ---------------- kernel 1: sort instances by image, build quad table ----------------
__global__ __launch_bounds__(512) void sortq(const int* __restrict__ im, int* __restrict__ qtab) {
    __shared__ int sorted[NINST];
    __shared__ int wtot0[8], wtot1[8], wex0[8], wex1[8];
    __shared__ int sc0;
    const int tid = threadIdx.x;
    const int lane = tid & 63, w = tid >> 6;
    const bool valid = tid < NINST;
    const int img = valid ? im[tid] : -1;
    const unsigned long long m0 = __ballot(valid && img == 0);
    const unsigned long long m1 = __ballot(valid && img == 1);
    const unsigned long long pm = (1ull << lane) - 1ull;
    const int pre0 = __popcll(m0 & pm);
    const int pre1 = __popcll(m1 & pm);
    if (lane == 0) { wtot0[w] = __popcll(m0); wtot1[w] = __popcll(m1); }
    __syncthreads();
    if (tid == 0) {
        int a = 0, b = 0;
        for (int i = 0; i < 8; ++i) { wex0[i] = a; a += wtot0[i]; wex1[i] = b; b += wtot1[i]; }
        sc0 = a;
    }
    __syncthreads();
    const int c0 = sc0;
    if (valid) {
        const int pos = (img == 0) ? (wex0[w] + pre0) : (c0 + wex1[w] + pre1);
        sorted[pos] = tid;
    }
    __syncthreads();
    if (tid < NQ) {
        const int c1 = NINST - c0;
        const int nq0 = (c0 + 3) >> 2, nq1 = (c1 + 3) >> 2;
        int i0 = -1, i1 = -1, i2 = -1, i3 = -1, qimg = 0;
        if (tid < nq0) {
            qimg = 0;
            int b = 4 * tid;
            if (b + 0 < c0) i0 = sorted[b + 0];
            if (b + 1 < c0) i1 = sorted[b + 1];
            if (b + 2 < c0) i2 = sorted[b + 2];
            if (b + 3 < c0) i3 = sorted[b + 3];
        } else if (tid < nq0 + nq1) {
            qimg = 1;
            int b = 4 * (tid - nq0);
            if (b + 0 < c1) i0 = sorted[c0 + b + 0];
            if (b + 1 < c1) i1 = sorted[c0 + b + 1];
            if (b + 2 < c1) i2 = sorted[c0 + b + 2];
            if (b + 3 < c1) i3 = sorted[c0 + b + 3];
        }
        qtab[tid * 5 + 0] = i0; qtab[tid * 5 + 1] = i1;
        qtab[tid * 5 + 2] = i2; qtab[tid * 5 + 3] = i3;
        qtab[tid * 5 + 4] = qimg;
    }
}

// ---------------- kernel 2: prepack per-quad MFMA fragments ----------------
__global__ __launch_bounds__(64) void prepack(
    const float* __restrict__ params, const float* __restrict__ locs,
    const float* __restrict__ soi, const int* __restrict__ qtab,
    uint8_t* __restrict__ frag)
{
    const int q = blockIdx.x, l = threadIdx.x;
    const int id0 = qtab[q * 5 + 0], id1 = qtab[q * 5 + 1];
    const int id2 = qtab[q * 5 + 2], id3 = qtab[q * 5 + 3];
    const int qimg = qtab[q * 5 + 4];
    uint8_t* base = frag + (size_t)q * QS;
    const int r = l & 31, half = l >> 5, i = r >> 3, c = r & 7;
    // select own-row instance without dynamic array indexing
    const int n = (i == 0) ? id0 : (i == 1) ? id1 : (i == 2) ? id2 : id3;
    const bool valid = n >= 0;
    const float* P = params + (size_t)(valid ? n : 0) * NPARAMS;
    float lx = 0.f, ly = 0.f, inv = 0.f;
    if (valid) { lx = locs[2 * n]; ly = locs[2 * n + 1]; inv = 1.0f / soi[n]; }
    const float wx = valid ? P[c * 10 + 0] : 0.f;
    const float wy = valid ? P[c * 10 + 1] : 0.f;
    const float b0 = valid ? P[152 + c] : 0.f;
    const float Cr = fmaf(wx, (lx - 4.0f) * inv, fmaf(wy, (ly - 4.0f) * inv, b0));
    const float Ex = -8.0f * wx * inv, Ey = -8.0f * wy * inv;
    const float Chi = (float)(__fp16)Cr, Clo = Cr - Chi;
    const float Xhi = (float)(__fp16)Ex, Xlo = Ex - Xhi;
    const float Yhi = (float)(__fp16)Ey, Ylo = Ey - Yhi;
    const int jb = half * 8;
    float v[8];
#pragma unroll
    for (int j = 0; j < 8; ++j) {
        const int k = jb + j;
        float x;
        if (k < 8)       x = valid ? P[c * 10 + 2 + k] : 0.f;
        else if (k == 8)  x = Chi;
        else if (k == 9)  x = Clo;
        else if (k == 10) x = Xhi;
        else if (k == 11) x = Xlo;
        else if (k == 12) x = Yhi;
        else if (k == 13) x = Ylo;
        else              x = 0.f;
        v[j] = x;
    }
    uint4 w0;
    w0.x = pkh(v[0], v[1]); w0.y = pkh(v[2], v[3]);
    w0.z = pkh(v[4], v[5]); w0.w = pkh(v[6], v[7]);
    *reinterpret_cast<uint4*>(base + l * 16) = w0;
    // A1a: k = 0..15
#pragma unroll
    for (int j = 0; j < 8; ++j) {
        const int k = jb + j;
        v[j] = (valid && (k >> 3) == i) ? P[80 + c * 8 + (k & 7)] : 0.f;
    }
    uint4 wa;
    wa.x = pkh(v[0], v[1]); wa.y = pkh(v[2], v[3]);
    wa.z = pkh(v[4], v[5]); wa.w = pkh(v[6], v[7]);
    *reinterpret_cast<uint4*>(base + 1024 + l * 16) = wa;
    // A1b: k = 16..31
#pragma unroll
    for (int j = 0; j < 8; ++j) {
        const int kk = 16 + jb + j;
        v[j] = (valid && (kk >> 3) == i) ? P[80 + c * 8 + (kk & 7)] : 0.f;
    }
    uint4 wb;
    wb.x = pkh(v[0], v[1]); wb.y = pkh(v[2], v[3]);
    wb.z = pkh(v[4], v[5]); wb.w = pkh(v[6], v[7]);
    *reinterpret_cast<uint4*>(base + 2048 + l * 16) = wb;
    // bias1 + w2 per-lane arrays: reg -> row = (reg&3) + 8*(reg>>2) + 4*half
    float bb[16], ww[16];
#pragma unroll
    for (int reg = 0; reg < 16; ++reg) {
        const int ii = reg >> 2;                       // row>>3 == reg>>2 (compile-time)
        const int cc = (reg & 3) + 4 * half;           // row&7
        const int nn = (ii == 0) ? id0 : (ii == 1) ? id1 : (ii == 2) ? id2 : id3;
        bb[reg] = (nn >= 0) ? params[(size_t)nn * NPARAMS + 160 + cc] : 0.f;
        ww[reg] = (nn >= 0) ? params[(size_t)nn * NPARAMS + 144 + cc] : 0.f;
    }
#pragma unroll
    for (int j = 0; j < 4; ++j) {
        float4 tb; tb.x = bb[4 * j]; tb.y = bb[4 * j + 1]; tb.z = bb[4 * j + 2]; tb.w = bb[4 * j + 3];
        *reinterpret_cast<float4*>(base + 3072 + l * 64 + 16 * j) = tb;
        float4 tw; tw.x = ww[4 * j]; tw.y = ww[4 * j + 1]; tw.z = ww[4 * j + 2]; tw.w = ww[4 * j + 3];
        *reinterpret_cast<float4*>(base + 7168 + l * 64 + 16 * j) = tw;
    }
    if (l < 4) {
        const int nn = (l == 0) ? id0 : (l == 1) ? id1 : (l == 2) ? id2 : id3;
        const uint32_t ofs = (nn >= 0) ? (uint32_t)(nn * HW * 4) : 0xFFFFFFFFu;
        *reinterpret_cast<uint32_t*>(base + 11264 + l * 4) = ofs;
        const float b2 = (nn >= 0) ? params[(size_t)nn * NPARAMS + 168] : 0.f;
        *reinterpret_cast<float*>(base + 11280 + l * 4) = b2;
    }
    if (l == 0) *reinterpret_cast<uint32_t*>(base + 11296) = (uint32_t)qimg;
}

// ---------------- kernel 3: main MFMA mask head ----------------
__global__ __launch_bounds__(256) void maskhead(
    const float* __restrict__ feats, const uint8_t* __restrict__ frag,
    float* __restrict__ out)
{
    const int wid = threadIdx.x >> 6, lane = threadIdx.x & 63;
    const int l31 = lane & 31, half = lane >> 5;
    const int sub = blockIdx.x * 4 + wid;
    if (sub >= 475) return;                      // no barriers used; safe early exit
    const int px = sub * 32 + l31;
    const int py = px / WID, ux = px - py * WID;

    // B0 fragments per image: lo half lanes carry k=0..7 (features),
    // hi half lanes carry k=8..15 = [1, 1, u, u, v, v, 0, 0]
    const uint32_t one2 = 0x3C003C00u;
    const uint32_t uu = pkh((float)ux, (float)ux);
    const uint32_t vv = pkh((float)py, (float)py);
    uint4 t0, t1;
    if (half == 0) {
        const float* fb0 = feats + px;
        const float* fb1 = feats + 8 * HW + px;
        float f[8], g[8];
#pragma unroll
        for (int ch = 0; ch < 8; ++ch) { f[ch] = fb0[(size_t)ch * HW]; g[ch] = fb1[(size_t)ch * HW]; }
        t0.x = pkh(f[0], f[1]); t0.y = pkh(f[2], f[3]); t0.z = pkh(f[4], f[5]); t0.w = pkh(f[6], f[7]);
        t1.x = pkh(g[0], g[1]); t1.y = pkh(g[2], g[3]); t1.z = pkh(g[4], g[5]); t1.w = pkh(g[6], g[7]);
    } else {
        t0.x = one2; t0.y = uu; t0.z = vv; t0.w = 0u;
        t1 = t0;
    }
    const f16x8 B0a = __builtin_bit_cast(f16x8, t0);
    const f16x8 B0b = __builtin_bit_cast(f16x8, t1);

    f32x16 z16;
#pragma unroll
    for (int e = 0; e < 16; ++e) z16[e] = 0.0f;

    const int qbase = blockIdx.y * 14;
    for (int t = 0; t < 14; ++t) {
        const uint8_t* qb = frag + (size_t)(qbase + t) * QS;
        const uint4 a0w  = *reinterpret_cast<const uint4*>(qb + lane * 16);
        const uint4 a1aw = *reinterpret_cast<const uint4*>(qb + 1024 + lane * 16);
        const uint4 a1bw = *reinterpret_cast<const uint4*>(qb + 2048 + lane * 16);
        const f32x16 bias = *reinterpret_cast<const f32x16*>(qb + 3072 + lane * 64);
        const f32x16 w2v  = *reinterpret_cast<const f32x16*>(qb + 7168 + lane * 64);
        const uint4 m0 = *reinterpret_cast<const uint4*>(qb + 11264);   // ofs[4]
        const uint4 m1 = *reinterpret_cast<const uint4*>(qb + 11280);   // b2[4]
        const uint32_t mimg = *reinterpret_cast<const uint32_t*>(qb + 11296);

        const f16x8 a0  = __builtin_bit_cast(f16x8, a0w);
        const f16x8 a1a = __builtin_bit_cast(f16x8, a1aw);
        const f16x8 a1b = __builtin_bit_cast(f16x8, a1bw);
        const f16x8 b0  = mimg ? B0b : B0a;

        // layer 0 (coords folded; bias folded via const rows)
        f32x16 acc0 = __builtin_amdgcn_mfma_f32_32x32x16_f16(a0, b0, z16, 0, 0, 0);

        // relu + f16 pack + cross-half swap -> B1 fragments
        uint32_t p0, p1, p2, p3, p4, p5, p6, p7;
        {
            float lo, hi;
            lo = fmaxf(acc0[0], 0.f);  hi = fmaxf(acc0[1], 0.f);
            p0 = __builtin_bit_cast(uint32_t, __builtin_amdgcn_cvt_pkrtz(lo, hi));
            lo = fmaxf(acc0[2], 0.f);  hi = fmaxf(acc0[3], 0.f);
            p1 = __builtin_bit_cast(uint32_t, __builtin_amdgcn_cvt_pkrtz(lo, hi));
            lo = fmaxf(acc0[4], 0.f);  hi = fmaxf(acc0[5], 0.f);
            p2 = __builtin_bit_cast(uint32_t, __builtin_amdgcn_cvt_pkrtz(lo, hi));
            lo = fmaxf(acc0[6], 0.f);  hi = fmaxf(acc0[7], 0.f);
            p3 = __builtin_bit_cast(uint32_t, __builtin_amdgcn_cvt_pkrtz(lo, hi));
            lo = fmaxf(acc0[8], 0.f);  hi = fmaxf(acc0[9], 0.f);
            p4 = __builtin_bit_cast(uint32_t, __builtin_amdgcn_cvt_pkrtz(lo, hi));
            lo = fmaxf(acc0[10], 0.f); hi = fmaxf(acc0[11], 0.f);
            p5 = __builtin_bit_cast(uint32_t, __builtin_amdgcn_cvt_pkrtz(lo, hi));
            lo = fmaxf(acc0[12], 0.f); hi = fmaxf(acc0[13], 0.f);
            p6 = __builtin_bit_cast(uint32_t, __builtin_amdgcn_cvt_pkrtz(lo, hi));
            lo = fmaxf(acc0[14], 0.f); hi = fmaxf(acc0[15], 0.f);
            p7 = __builtin_bit_cast(uint32_t, __builtin_amdgcn_cvt_pkrtz(lo, hi));
        }
        uint32_t x0 = p0, y0 = p2; asm("v_permlane32_swap_b32 %0, %1" : "+v"(x0), "+v"(y0));
        uint32_t x1 = p1, y1 = p3; asm("v_permlane32_swap_b32 %0, %1" : "+v"(x1), "+v"(y1));
        uint32_t x2 = p4, y2 = p6; asm("v_permlane32_swap_b32 %0, %1" : "+v"(x2), "+v"(y2));
        uint32_t x3 = p5, y3 = p7; asm("v_permlane32_swap_b32 %0, %1" : "+v"(x3), "+v"(y3));
        uint4 ba; ba.x = x0; ba.y = x1; ba.z = y0; ba.w = y1;
        uint4 bbv; bbv.x = x2; bbv.y = x3; bbv.z = y2; bbv.w = y3;
        const f16x8 b1a = __builtin_bit_cast(f16x8, ba);
        const f16x8 b1b = __builtin_bit_cast(f16x8, bbv);

        // layer 1 (bias via C operand)
        f32x16 acc1 = __builtin_amdgcn_mfma_f32_32x32x16_f16(a1a, b1a, bias, 0, 0, 0);
        acc1 = __builtin_amdgcn_mfma_f32_32x32x16_f16(a1b, b1b, acc1, 0, 0, 0);

        // layer 2 on VALU: per instance i, dot over its 4 held channels + cross-half reduce
        float s0, s1, s2, s3;
#define L2I(I, SV)                                                                      \
        {                                                                               \
            const float h0_ = fmaxf(acc1[4 * I + 0], 0.f);                              \
            const float h1_ = fmaxf(acc1[4 * I + 1], 0.f);                              \
            const float h2_ = fmaxf(acc1[4 * I + 2], 0.f);                              \
            const float h3_ = fmaxf(acc1[4 * I + 3], 0.f);                              \
            SV = fmaf(w2v[4 * I + 0], h0_, fmaf(w2v[4 * I + 1], h1_,                    \
                 fmaf(w2v[4 * I + 2], h2_, w2v[4 * I + 3] * h3_)));                     \
            SV += __shfl_xor(SV, 32);                                                   \
        }
        L2I(0, s0) L2I(1, s1) L2I(2, s2) L2I(3, s3)
#undef L2I
        s0 += __builtin_bit_cast(float, m1.x);
        s1 += __builtin_bit_cast(float, m1.y);
        s2 += __builtin_bit_cast(float, m1.z);
        s3 += __builtin_bit_cast(float, m1.w);

        if (lane < 32) {
            if (m0.x != 0xFFFFFFFFu) out[(m0.x >> 2) + px] = s0;
            if (m0.y != 0xFFFFFFFFu) out[(m0.y >> 2) + px] = s1;
            if (m0.z != 0xFFFFFFFFu) out[(m0.z >> 2) + px] = s2;
            if (m0.w != 0xFFFFFFFFu) out[(m0.w >> 2) + px] = s3;
        }
    }
}

extern "C" void kernel_launch(void* const* d_in, const int* in_sizes, int n_in,
                              void* d_out, int out_size, void* d_ws, size_t ws_size,
                              hipStream_t stream) {
    const float* feats   = (const float*)d_in[0];  // mask_feats [2,8,100,152]
    const float* params  = (const float*)d_in[1];  // mask_head_params [500,169]
    const float* locs    = (const float*)d_in[2];  // instance_locations [500,2]
    const float* soi     = (const float*)d_in[3];  // soi [500]
    const int*   im_inds = (const int*)d_in[4];    // im_inds [500]
    float*       out     = (float*)d_out;          // [500,1,100,152]

    int*     qtab = (int*)d_ws;
    uint8_t* frag = (uint8_t*)d_ws + FRAG_OFS;     // needs 4096 + 126*12288 ~ 1.55 MB

    sortq<<<1, 512, 0, stream>>>(im_inds, qtab);
    prepack<<<NQ, 64, 0, stream>>>(params, locs, soi, qtab, frag);
    maskhead<<<dim3(119, 9), 256, 0, stream>>>(feats, frag, out);
}

// Round 10
// 35.506 us; speedup vs baseline: 1.6905x; 1.6905x over previous
//
#include <hip/hip_runtime.h>
#include <stdint.h>

#define HGT 100
#define WID 152
#define HW (HGT * WID)        // 15200
#define NINST 500
#define NPARAMS 169
#define NQ 126                // quad slots (<=126 for 500 instances split by image)
#define QS 4096               // bytes per quad in frag region
#define NSUB 475              // 15200 / 32 pixel subtiles
#define GSUB 12               // subtile groups in grid.x

// per-quad frag layout (bytes):
//   A0   @0     (64 lanes * 16B)  layer0 A-frag, K=16: [f0..f7, Chi, Clo, Exhi, Exlo, Eyhi, Eylo, 0, 0]
//   A1a  @1024  (64*16)           layer1 A-frag k=0..15  (block-diag W1, inst 0,1)
//   A1b  @2048  (64*16)           layer1 A-frag k=16..31 (inst 2,3)
//   bias1@3072  (2 halves * 64B)  f32x16 C-operand rows (per lane-half, broadcast)
//   w2   @3200  (2 halves * 64B)  f32x16 layer2 weights (per lane-half, broadcast)
//   meta @3328  u32 ofs[4] (n*HW*4 or -1) @3328, f32 b2[4] @3344, u32 img @3360

typedef __fp16 f16x8  __attribute__((ext_vector_type(8)));
typedef float  f32x16 __attribute__((ext_vector_type(16)));

static __device__ __forceinline__ uint32_t pkh(float lo, float hi) {
    __fp16 a = (__fp16)lo, b = (__fp16)hi;   // RNE
    uint16_t ua = __builtin_bit_cast(uint16_t, a);
    uint16_t ub = __builtin_bit_cast(uint16_t, b);
    return (uint32_t)ua | ((uint32_t)ub << 16);
}

// ------------- kernel 1: per-block redundant image-sort + prepack 8 quads -------------
__global__ __launch_bounds__(512) void preall(
    const float* __restrict__ params, const float* __restrict__ locs,
    const float* __restrict__ soi, const int* __restrict__ im,
    uint8_t* __restrict__ frag)
{
    __shared__ int sorted[NINST];
    __shared__ int wtot0[8], wtot1[8], wex0[8], wex1[8];
    __shared__ int sc0;
    const int tid = threadIdx.x;
    const int lane = tid & 63, w = tid >> 6;
    // ---- sort phase (every block redoes it; ~500 threads, trivial) ----
    const bool svalid = tid < NINST;
    const int img = svalid ? im[tid] : -1;
    const unsigned long long m0s = __ballot(svalid && img == 0);
    const unsigned long long m1s = __ballot(svalid && img == 1);
    const unsigned long long pm = (1ull << lane) - 1ull;
    const int pre0 = __popcll(m0s & pm);
    const int pre1 = __popcll(m1s & pm);
    if (lane == 0) { wtot0[w] = __popcll(m0s); wtot1[w] = __popcll(m1s); }
    __syncthreads();
    if (tid == 0) {
        int a = 0, b = 0;
        for (int i = 0; i < 8; ++i) { wex0[i] = a; a += wtot0[i]; wex1[i] = b; b += wtot1[i]; }
        sc0 = a;
    }
    __syncthreads();
    const int c0 = sc0;
    if (svalid) {
        const int pos = (img == 0) ? (wex0[w] + pre0) : (c0 + wex1[w] + pre1);
        sorted[pos] = tid;
    }
    __syncthreads();

    // ---- prepack phase: this block packs quads [bx*8, bx*8+8), one per wave ----
    const int q = blockIdx.x * 8 + w;
    if (q >= NQ) return;
    const int c1 = NINST - c0;
    const int nq0 = (c0 + 3) >> 2, nq1 = (c1 + 3) >> 2;
    int id0 = -1, id1 = -1, id2 = -1, id3 = -1, qimg = 0;
    if (q < nq0) {
        const int b = 4 * q;
        if (b + 0 < c0) id0 = sorted[b + 0];
        if (b + 1 < c0) id1 = sorted[b + 1];
        if (b + 2 < c0) id2 = sorted[b + 2];
        if (b + 3 < c0) id3 = sorted[b + 3];
    } else if (q < nq0 + nq1) {
        qimg = 1;
        const int b = 4 * (q - nq0);
        if (b + 0 < c1) id0 = sorted[c0 + b + 0];
        if (b + 1 < c1) id1 = sorted[c0 + b + 1];
        if (b + 2 < c1) id2 = sorted[c0 + b + 2];
        if (b + 3 < c1) id3 = sorted[c0 + b + 3];
    }
    uint8_t* base = frag + (size_t)q * QS;
    const int l = lane;
    const int r = l & 31, half = l >> 5, i = r >> 3, c = r & 7;
    const int n = (i == 0) ? id0 : (i == 1) ? id1 : (i == 2) ? id2 : id3;
    const bool valid = n >= 0;
    const float* P = params + (size_t)(valid ? n : 0) * NPARAMS;
    float lx = 0.f, ly = 0.f, inv = 0.f;
    if (valid) { lx = locs[2 * n]; ly = locs[2 * n + 1]; inv = 1.0f / soi[n]; }
    const float wx = valid ? P[c * 10 + 0] : 0.f;
    const float wy = valid ? P[c * 10 + 1] : 0.f;
    const float b0 = valid ? P[152 + c] : 0.f;
    const float Cr = fmaf(wx, (lx - 4.0f) * inv, fmaf(wy, (ly - 4.0f) * inv, b0));
    const float Ex = -8.0f * wx * inv, Ey = -8.0f * wy * inv;
    const float Chi = (float)(__fp16)Cr, Clo = Cr - Chi;
    const float Xhi = (float)(__fp16)Ex, Xlo = Ex - Xhi;
    const float Yhi = (float)(__fp16)Ey, Ylo = Ey - Yhi;
    const int jb = half * 8;
    float v[8];
#pragma unroll
    for (int j = 0; j < 8; ++j) {
        const int k = jb + j;
        float x;
        if (k < 8)        x = valid ? P[c * 10 + 2 + k] : 0.f;
        else if (k == 8)  x = Chi;
        else if (k == 9)  x = Clo;
        else if (k == 10) x = Xhi;
        else if (k == 11) x = Xlo;
        else if (k == 12) x = Yhi;
        else if (k == 13) x = Ylo;
        else              x = 0.f;
        v[j] = x;
    }
    uint4 w0;
    w0.x = pkh(v[0], v[1]); w0.y = pkh(v[2], v[3]);
    w0.z = pkh(v[4], v[5]); w0.w = pkh(v[6], v[7]);
    *reinterpret_cast<uint4*>(base + l * 16) = w0;
#pragma unroll
    for (int j = 0; j < 8; ++j) {
        const int k = jb + j;
        v[j] = (valid && (k >> 3) == i) ? P[80 + c * 8 + (k & 7)] : 0.f;
    }
    uint4 wa;
    wa.x = pkh(v[0], v[1]); wa.y = pkh(v[2], v[3]);
    wa.z = pkh(v[4], v[5]); wa.w = pkh(v[6], v[7]);
    *reinterpret_cast<uint4*>(base + 1024 + l * 16) = wa;
#pragma unroll
    for (int j = 0; j < 8; ++j) {
        const int kk = 16 + jb + j;
        v[j] = (valid && (kk >> 3) == i) ? P[80 + c * 8 + (kk & 7)] : 0.f;
    }
    uint4 wb;
    wb.x = pkh(v[0], v[1]); wb.y = pkh(v[2], v[3]);
    wb.z = pkh(v[4], v[5]); wb.w = pkh(v[6], v[7]);
    *reinterpret_cast<uint4*>(base + 2048 + l * 16) = wb;
    // bias1/w2: depend only on (reg, half) -> one writer lane per half
    if (r == 0) {
        float bb[16], ww[16];
#pragma unroll
        for (int reg = 0; reg < 16; ++reg) {
            const int ii = reg >> 2;
            const int cc = (reg & 3) + 4 * half;
            const int nn = (ii == 0) ? id0 : (ii == 1) ? id1 : (ii == 2) ? id2 : id3;
            bb[reg] = (nn >= 0) ? params[(size_t)nn * NPARAMS + 160 + cc] : 0.f;
            ww[reg] = (nn >= 0) ? params[(size_t)nn * NPARAMS + 144 + cc] : 0.f;
        }
#pragma unroll
        for (int j = 0; j < 4; ++j) {
            float4 tb; tb.x = bb[4*j]; tb.y = bb[4*j+1]; tb.z = bb[4*j+2]; tb.w = bb[4*j+3];
            *reinterpret_cast<float4*>(base + 3072 + half * 64 + 16 * j) = tb;
            float4 tw; tw.x = ww[4*j]; tw.y = ww[4*j+1]; tw.z = ww[4*j+2]; tw.w = ww[4*j+3];
            *reinterpret_cast<float4*>(base + 3200 + half * 64 + 16 * j) = tw;
        }
    }
    if (l < 4) {
        const int nn = (l == 0) ? id0 : (l == 1) ? id1 : (l == 2) ? id2 : id3;
        const uint32_t ofs = (nn >= 0) ? (uint32_t)(nn * HW * 4) : 0xFFFFFFFFu;
        *reinterpret_cast<uint32_t*>(base + 3328 + l * 4) = ofs;
        const float b2 = (nn >= 0) ? params[(size_t)nn * NPARAMS + 168] : 0.f;
        *reinterpret_cast<float*>(base + 3344 + l * 4) = b2;
    }
    if (l == 0) *reinterpret_cast<uint32_t*>(base + 3360) = (uint32_t)qimg;
}

// ------------- kernel 2: main MFMA mask head (quad-resident, loop over pixels) -------------
__global__ __launch_bounds__(256, 4) void maskhead(
    const float* __restrict__ feats, const uint8_t* __restrict__ frag,
    float* __restrict__ out)
{
    const int wid = threadIdx.x >> 6, lane = threadIdx.x & 63;
    const int l31 = lane & 31, half = lane >> 5;

    // one-time per-quad fragment loads -> registers
    const uint8_t* qb = frag + (size_t)blockIdx.y * QS;
    const uint4 a0w  = *reinterpret_cast<const uint4*>(qb + lane * 16);
    const uint4 a1aw = *reinterpret_cast<const uint4*>(qb + 1024 + lane * 16);
    const uint4 a1bw = *reinterpret_cast<const uint4*>(qb + 2048 + lane * 16);
    const f32x16 bias = *reinterpret_cast<const f32x16*>(qb + 3072 + half * 64);
    const f32x16 w2v  = *reinterpret_cast<const f32x16*>(qb + 3200 + half * 64);
    const uint4 m0 = *reinterpret_cast<const uint4*>(qb + 3328);   // ofs[4]
    const uint4 m1 = *reinterpret_cast<const uint4*>(qb + 3344);   // b2[4]
    const uint32_t mimg = *reinterpret_cast<const uint32_t*>(qb + 3360);
    const f16x8 a0  = __builtin_bit_cast(f16x8, a0w);
    const f16x8 a1a = __builtin_bit_cast(f16x8, a1aw);
    const f16x8 a1b = __builtin_bit_cast(f16x8, a1bw);
    const float* fbase = feats + (size_t)mimg * 8 * HW;

    f32x16 z16;
#pragma unroll
    for (int e = 0; e < 16; ++e) z16[e] = 0.0f;
    const uint32_t one2 = 0x3C003C00u;

    for (int sub = blockIdx.x * 4 + wid; sub < NSUB; sub += GSUB * 4) {
        const int px = sub * 32 + l31;
        const int py = px / WID, ux = px - py * WID;

        // B0: lo-half lanes carry k=0..7 (features), hi-half k=8..15 = [1,1,u,u,v,v,0,0]
        uint4 t0;
        if (half == 0) {
            const float* fp = fbase + px;
            float f[8];
#pragma unroll
            for (int ch = 0; ch < 8; ++ch) f[ch] = fp[(size_t)ch * HW];
            t0.x = pkh(f[0], f[1]); t0.y = pkh(f[2], f[3]);
            t0.z = pkh(f[4], f[5]); t0.w = pkh(f[6], f[7]);
        } else {
            t0.x = one2; t0.y = pkh((float)ux, (float)ux);
            t0.z = pkh((float)py, (float)py); t0.w = 0u;
        }
        const f16x8 b0 = __builtin_bit_cast(f16x8, t0);

        // layer 0 (coords + bias0 folded into A0 const rows)
        f32x16 acc0 = __builtin_amdgcn_mfma_f32_32x32x16_f16(a0, b0, z16, 0, 0, 0);

        // relu + f16 pack + cross-half swap -> B1 fragments
        uint32_t p0, p1, p2, p3, p4, p5, p6, p7;
        {
            float lo, hi;
            lo = fmaxf(acc0[0], 0.f);  hi = fmaxf(acc0[1], 0.f);
            p0 = __builtin_bit_cast(uint32_t, __builtin_amdgcn_cvt_pkrtz(lo, hi));
            lo = fmaxf(acc0[2], 0.f);  hi = fmaxf(acc0[3], 0.f);
            p1 = __builtin_bit_cast(uint32_t, __builtin_amdgcn_cvt_pkrtz(lo, hi));
            lo = fmaxf(acc0[4], 0.f);  hi = fmaxf(acc0[5], 0.f);
            p2 = __builtin_bit_cast(uint32_t, __builtin_amdgcn_cvt_pkrtz(lo, hi));
            lo = fmaxf(acc0[6], 0.f);  hi = fmaxf(acc0[7], 0.f);
            p3 = __builtin_bit_cast(uint32_t, __builtin_amdgcn_cvt_pkrtz(lo, hi));
            lo = fmaxf(acc0[8], 0.f);  hi = fmaxf(acc0[9], 0.f);
            p4 = __builtin_bit_cast(uint32_t, __builtin_amdgcn_cvt_pkrtz(lo, hi));
            lo = fmaxf(acc0[10], 0.f); hi = fmaxf(acc0[11], 0.f);
            p5 = __builtin_bit_cast(uint32_t, __builtin_amdgcn_cvt_pkrtz(lo, hi));
            lo = fmaxf(acc0[12], 0.f); hi = fmaxf(acc0[13], 0.f);
            p6 = __builtin_bit_cast(uint32_t, __builtin_amdgcn_cvt_pkrtz(lo, hi));
            lo = fmaxf(acc0[14], 0.f); hi = fmaxf(acc0[15], 0.f);
            p7 = __builtin_bit_cast(uint32_t, __builtin_amdgcn_cvt_pkrtz(lo, hi));
        }
        uint32_t x0 = p0, y0 = p2; asm("v_permlane32_swap_b32 %0, %1" : "+v"(x0), "+v"(y0));
        uint32_t x1 = p1, y1 = p3; asm("v_permlane32_swap_b32 %0, %1" : "+v"(x1), "+v"(y1));
        uint32_t x2 = p4, y2 = p6; asm("v_permlane32_swap_b32 %0, %1" : "+v"(x2), "+v"(y2));
        uint32_t x3 = p5, y3 = p7; asm("v_permlane32_swap_b32 %0, %1" : "+v"(x3), "+v"(y3));
        uint4 ba;  ba.x = x0;  ba.y = x1;  ba.z = y0;  ba.w = y1;
        uint4 bbv; bbv.x = x2; bbv.y = x3; bbv.z = y2; bbv.w = y3;
        const f16x8 b1a = __builtin_bit_cast(f16x8, ba);
        const f16x8 b1b = __builtin_bit_cast(f16x8, bbv);

        // layer 1 (bias via C operand)
        f32x16 acc1 = __builtin_amdgcn_mfma_f32_32x32x16_f16(a1a, b1a, bias, 0, 0, 0);
        acc1 = __builtin_amdgcn_mfma_f32_32x32x16_f16(a1b, b1b, acc1, 0, 0, 0);

        // layer 2 on VALU: per instance i, dot over its 4 held channels + cross-half reduce
        float s0, s1, s2, s3;
#define L2I(I, SV)                                                                      \
        {                                                                               \
            const float h0_ = fmaxf(acc1[4 * I + 0], 0.f);                              \
            const float h1_ = fmaxf(acc1[4 * I + 1], 0.f);                              \
            const float h2_ = fmaxf(acc1[4 * I + 2], 0.f);                              \
            const float h3_ = fmaxf(acc1[4 * I + 3], 0.f);                              \
            SV = fmaf(w2v[4 * I + 0], h0_, fmaf(w2v[4 * I + 1], h1_,                    \
                 fmaf(w2v[4 * I + 2], h2_, w2v[4 * I + 3] * h3_)));                     \
            SV += __shfl_xor(SV, 32);                                                   \
        }
        L2I(0, s0) L2I(1, s1) L2I(2, s2) L2I(3, s3)
#undef L2I
        s0 += __builtin_bit_cast(float, m1.x);
        s1 += __builtin_bit_cast(float, m1.y);
        s2 += __builtin_bit_cast(float, m1.z);
        s3 += __builtin_bit_cast(float, m1.w);

        if (lane < 32) {
            if (m0.x != 0xFFFFFFFFu) out[(m0.x >> 2) + px] = s0;
            if (m0.y != 0xFFFFFFFFu) out[(m0.y >> 2) + px] = s1;
            if (m0.z != 0xFFFFFFFFu) out[(m0.z >> 2) + px] = s2;
            if (m0.w != 0xFFFFFFFFu) out[(m0.w >> 2) + px] = s3;
        }
    }
}

extern "C" void kernel_launch(void* const* d_in, const int* in_sizes, int n_in,
                              void* d_out, int out_size, void* d_ws, size_t ws_size,
                              hipStream_t stream) {
    const float* feats   = (const float*)d_in[0];  // mask_feats [2,8,100,152]
    const float* params  = (const float*)d_in[1];  // mask_head_params [500,169]
    const float* locs    = (const float*)d_in[2];  // instance_locations [500,2]
    const float* soi     = (const float*)d_in[3];  // soi [500]
    const int*   im_inds = (const int*)d_in[4];    // im_inds [500]
    float*       out     = (float*)d_out;          // [500,1,100,152]

    uint8_t* frag = (uint8_t*)d_ws;                // NQ*QS = 516 KB

    preall<<<(NQ + 7) / 8, 512, 0, stream>>>(params, locs, soi, im_inds, frag);
    maskhead<<<dim3(GSUB, NQ), 256, 0, stream>>>(feats, frag, out);
}